// Round 5
// baseline (217.403 us; speedup 1.0000x reference)
//
#include <hip/hip_runtime.h>
#include <hip/hip_bf16.h>

// Problem constants (fixed by setup_inputs): B=4, N=16384, M=128, C=128, S=512.
// Output layout (float32): pooled (B*M*S*(C+3)) then empty_flag (B*M) as 0.0/1.0.
#define BB   4
#define NN   16384
#define MM   128
#define CC   128
#define SS   512
#define CH   (CC + 3)      // 131
#define BM   (BB * MM)     // 512
#define WAVES 8            // waves per block
#define CHUNK (NN / WAVES) // 2048 points per wave

typedef float vfloat4 __attribute__((ext_vector_type(4)));  // true vector type
                                                            // (nontemporal builtin
                                                            // rejects HIP float4 class)

// ---------------------------------------------------------------------------
// Fused kernel: one block (8 waves, 512 thr) per box.
// Phase A: each wave stably compacts its contiguous 2048-point chunk into an
//   LDS segment; block merges segments by prefix offsets (stable order),
//   wrap-fills idx[k]=idx[k%cnt] in s_idx, writes empty_flag.
//   Rotation test in double (true value >> fp32 ref roundoff -> same side of
//   every boundary as the np ref); z-test fp32, bit-identical to numpy.
// Phase B: gather, 8 groups of 64 samples. float4 gathers from feats staged
//   into an LDS image of the group's 33536-B output span (reusing phase-A's
//   s_part memory), then perfectly coalesced float4 NONTEMPORAL stores (keep
//   the 137 MB output stream from evicting the 8 MB/batch feature table
//   out of per-XCD L2).
// ---------------------------------------------------------------------------
__global__ __launch_bounds__(512)
void roipool_fused_kernel(const float* __restrict__ points,  // (B,N,3)
                          const float* __restrict__ feats,   // (B,N,C)
                          const float* __restrict__ boxes,   // (B,M,7)
                          float* __restrict__ out,           // (BM,SS,CH)
                          float* __restrict__ flag_out)      // (BM)
{
    const int box  = blockIdx.x;          // b*MM + m
    const int b    = box >> 7;            // MM = 128
    const int tid  = threadIdx.x;
    const int lane = tid & 63;
    const int w    = tid >> 6;            // wave 0..7

    const float* P  = points + (size_t)b * NN * 3;
    const float* bx = boxes  + (size_t)box * 7;

    const float cx = bx[0], cy = bx[1], cz = bx[2];
    const float dx = bx[3], dy = bx[4], dz = bx[5], rz = bx[6];

    const float  czc = cz + dz * 0.5f;     // exact
    const float  hz  = dz * 0.5f;          // exact
    const double ca  = cos(-(double)rz);
    const double sa  = sin(-(double)rz);
    const double hx  = (double)dx * 0.5;
    const double hy  = (double)dy * 0.5;

    // Phase-B staging buffer; its first 16 KB double as phase-A s_part.
    __shared__ __align__(16) float s_buf[64 * CH];   // 33536 B
    __shared__ int s_idx[SS];                        // 2048 B
    __shared__ int s_cnt[WAVES];
    int (*s_part)[SS] = (int (*)[SS])s_buf;          // [WAVES][SS] = 16384 B

    // ---------------- Phase A: stable per-wave compaction ----------------
    int cnt = 0;
    const int pbase = w * CHUNK;
    for (int i0 = 0; i0 < CHUNK; i0 += 256) {        // 8 outer iterations
        float px[4], py[4], pz[4];
        #pragma unroll
        for (int u = 0; u < 4; ++u) {
            const int i = pbase + i0 + u * 64 + lane;
            px[u] = P[i * 3 + 0];
            py[u] = P[i * 3 + 1];
            pz[u] = P[i * 3 + 2];
        }
        #pragma unroll
        for (int u = 0; u < 4; ++u) {
            const double sx = (double)px[u] - (double)cx;
            const double sy = (double)py[u] - (double)cy;
            const float  szf = pz[u] - czc;
            const double lx = sx * ca - sy * sa;
            const double ly = sx * sa + sy * ca;
            const bool inside = (fabs(lx) < hx) && (fabs(ly) < hy) && (fabsf(szf) <= hz);
            const unsigned long long mask = __ballot(inside);
            const int pos = cnt + __popcll(mask & ((1ull << lane) - 1ull));
            if (inside && pos < SS) s_part[w][pos] = pbase + i0 + u * 64 + lane;
            cnt += __popcll(mask);
        }
    }
    if (lane == 0) s_cnt[w] = cnt;
    __syncthreads();

    int c[WAVES], off[WAVES];
    int total = 0;
    #pragma unroll
    for (int q = 0; q < WAVES; ++q) { c[q] = s_cnt[q]; off[q] = total; total += c[q]; }

    // merge segments into first min(total,SS) slots, stable order
    for (int k = tid; k < SS; k += 512) {
        int v = 0;
        #pragma unroll
        for (int q = 0; q < WAVES; ++q) {
            const int r = k - off[q];
            if (r >= 0 && r < c[q]) v = s_part[q][r];
        }
        s_idx[k] = v;
    }
    __syncthreads();     // s_idx complete; s_part reads done (s_buf reusable)

    if (total > 0 && total < SS) {
        for (int k = total + tid; k < SS; k += 512)
            s_idx[k] = s_idx[k % total];
    }
    __syncthreads();

    const float scale = (total > 0) ? 1.0f : 0.0f;
    if (tid == 0) flag_out[box] = (total == 0) ? 1.0f : 0.0f;

    // ---------------- Phase B: staged gather + coalesced nt stores --------
    const float4* F4 = (const float4*)(feats + (size_t)b * NN * CC);
    const float*  Pb = P;
    const int hw = tid >> 5;          // half-wave 0..15
    const int j  = tid & 31;          // lane in half-wave
    float* outbox = out + (size_t)box * SS * CH;

    for (int g = 0; g < 8; ++g) {     // 8 groups of 64 samples
        #pragma unroll
        for (int s = 0; s < 4; ++s) {
            const int kl  = s * 16 + hw;          // sample in group, 0..63
            const int idx = s_idx[g * 64 + kl];
            const float4 v = F4[idx * 32 + j];
            const int base = kl * CH + 3 + 4 * j;
            s_buf[base + 0] = v.x * scale;
            s_buf[base + 1] = v.y * scale;
            s_buf[base + 2] = v.z * scale;
            s_buf[base + 3] = v.w * scale;
            if (j < 3) s_buf[kl * CH + j] = Pb[idx * 3 + j] * scale;
        }
        __syncthreads();

        const vfloat4* src4 = (const vfloat4*)s_buf;
        vfloat4* dst4 = (vfloat4*)(outbox + (size_t)g * 64 * CH);  // 16B-aligned span
        #pragma unroll
        for (int s = 0; s < 4; ++s)
            __builtin_nontemporal_store(src4[s * 512 + tid], &dst4[s * 512 + tid]);
        if (tid < 48)
            __builtin_nontemporal_store(src4[2048 + tid], &dst4[2048 + tid]);  // 2096 total
        __syncthreads();
    }
}

extern "C" void kernel_launch(void* const* d_in, const int* in_sizes, int n_in,
                              void* d_out, int out_size, void* d_ws, size_t ws_size,
                              hipStream_t stream) {
    const float* points = (const float*)d_in[0];
    const float* feats  = (const float*)d_in[1];
    const float* boxes  = (const float*)d_in[2];
    // d_in[3] = num_sampled_points, fixed at 512 by setup_inputs.

    float* out      = (float*)d_out;
    float* flag_out = out + (size_t)BM * SS * CH;    // empty_flag as float 0/1

    roipool_fused_kernel<<<BM, 512, 0, stream>>>(points, feats, boxes, out, flag_out);
}

// Round 6
// 204.758 us; speedup vs baseline: 1.0618x; 1.0618x over previous
//
#include <hip/hip_runtime.h>
#include <hip/hip_bf16.h>

// Problem constants (fixed by setup_inputs): B=4, N=16384, M=128, C=128, S=512.
// Output layout (float32): pooled (B*M*S*(C+3)) then empty_flag (B*M) as 0.0/1.0.
#define BB   4
#define NN   16384
#define MM   128
#define CC   128
#define SS   512
#define CH   (CC + 3)      // 131
#define BM   (BB * MM)     // 512
#define WAVES 8            // waves per box in kernel A
#define CHUNK (NN / WAVES) // 2048 points per wave

typedef float vfloat4 __attribute__((ext_vector_type(4)));  // nontemporal builtin
                                                            // rejects HIP float4 class

// ---------------------------------------------------------------------------
// Kernel A: one block (8 waves, 512 thr) per box. Each wave stably compacts
// its contiguous 2048-point chunk into an LDS segment; block merges segments
// by prefix offsets (stable), wrap-fills idx[k]=idx[k%cnt], writes idx/flag.
// Rotation test in double (true value >> fp32 ref roundoff); z-test fp32,
// bit-identical to numpy.
// NOTE R5 lesson: do NOT fuse A+B — fused phase-B loses 8x gather TLP and
// regressed 197.7 -> 217.4 us.
// ---------------------------------------------------------------------------
__global__ __launch_bounds__(512)
void box_sample_kernel(const float* __restrict__ points,  // (B,N,3)
                       const float* __restrict__ boxes,   // (B,M,7)
                       int*  __restrict__ idx_ws,         // (BM,SS)
                       int*  __restrict__ cnt_ws,         // (BM)
                       float* __restrict__ flag_out)      // (BM)
{
    const int box  = blockIdx.x;          // b*MM + m
    const int b    = box >> 7;            // MM = 128
    const int lane = threadIdx.x & 63;
    const int w    = threadIdx.x >> 6;    // wave 0..7

    const float* P  = points + (size_t)b * NN * 3;
    const float* bx = boxes  + (size_t)box * 7;

    const float cx = bx[0], cy = bx[1], cz = bx[2];
    const float dx = bx[3], dy = bx[4], dz = bx[5], rz = bx[6];

    const float  czc = cz + dz * 0.5f;     // exact
    const float  hz  = dz * 0.5f;          // exact
    const double ca  = cos(-(double)rz);
    const double sa  = sin(-(double)rz);
    const double hx  = (double)dx * 0.5;
    const double hy  = (double)dy * 0.5;

    __shared__ int s_part[WAVES][SS];     // 16 KB
    __shared__ int s_cnt[WAVES];
    __shared__ int s_idx[SS];

    int cnt = 0;
    const int pbase = w * CHUNK;
    for (int i0 = 0; i0 < CHUNK; i0 += 256) {     // 8 outer iterations
        float px[4], py[4], pz[4];
        #pragma unroll
        for (int u = 0; u < 4; ++u) {
            const int i = pbase + i0 + u * 64 + lane;
            px[u] = P[i * 3 + 0];
            py[u] = P[i * 3 + 1];
            pz[u] = P[i * 3 + 2];
        }
        #pragma unroll
        for (int u = 0; u < 4; ++u) {
            const double sx = (double)px[u] - (double)cx;
            const double sy = (double)py[u] - (double)cy;
            const float  szf = pz[u] - czc;
            const double lx = sx * ca - sy * sa;
            const double ly = sx * sa + sy * ca;
            const bool inside = (fabs(lx) < hx) && (fabs(ly) < hy) && (fabsf(szf) <= hz);
            const unsigned long long mask = __ballot(inside);
            const int pos = cnt + __popcll(mask & ((1ull << lane) - 1ull));
            if (inside && pos < SS) s_part[w][pos] = pbase + i0 + u * 64 + lane;
            cnt += __popcll(mask);
        }
    }
    if (lane == 0) s_cnt[w] = cnt;
    __syncthreads();

    int c[WAVES], off[WAVES];
    int total = 0;
    #pragma unroll
    for (int q = 0; q < WAVES; ++q) { c[q] = s_cnt[q]; off[q] = total; total += c[q]; }

    // merge segments into first min(total,SS) slots, stable order
    for (int k = threadIdx.x; k < SS; k += 512) {
        int v = 0;
        #pragma unroll
        for (int q = 0; q < WAVES; ++q) {
            const int r = k - off[q];
            if (r >= 0 && r < c[q]) v = s_part[q][r];
        }
        s_idx[k] = v;
    }
    __syncthreads();

    if (total > 0 && total < SS) {
        for (int k = total + threadIdx.x; k < SS; k += 512)
            s_idx[k] = s_idx[k % total];
        __syncthreads();
    }

    int* dst = idx_ws + (size_t)box * SS;
    for (int k = threadIdx.x; k < SS; k += 512) dst[k] = s_idx[k];
    if (threadIdx.x == 0) {
        cnt_ws[box]   = total;
        flag_out[box] = (total == 0) ? 1.0f : 0.0f;
    }
}

// ---------------------------------------------------------------------------
// Kernel B: gather. Grid (512 boxes, 16 chunks of 32 samples); 256 threads.
// Phase 1: float4 gathers from feats (coalesced 512B per half-wave per row)
// staged into an LDS image of the chunk's 4192-float output span. Phase 2:
// perfectly coalesced float4 NONTEMPORAL stores — the 137 MB output stream
// must not evict the 32 MB feature table from per-XCD L2.
// ---------------------------------------------------------------------------
__global__ __launch_bounds__(256)
void gather_kernel(const float* __restrict__ points,   // (B,N,3)
                   const float* __restrict__ feats,    // (B,N,C)
                   const int*   __restrict__ idx_ws,   // (BM,SS)
                   const int*   __restrict__ cnt_ws,   // (BM)
                   float* __restrict__ out)            // (BM,SS,CH)
{
    const int box   = blockIdx.x;         // 0..511
    const int chunk = blockIdx.y;         // 0..15
    const int b     = box >> 7;
    const int tid   = threadIdx.x;
    const int hw    = tid >> 5;           // half-wave 0..7
    const int j     = tid & 31;           // lane in half-wave

    __shared__ int   s_idx[32];
    __shared__ float s_scale;
    __shared__ __align__(16) float s_buf[32 * CH];   // 4192 floats = 16768 B

    if (tid < 32) s_idx[tid] = idx_ws[(size_t)box * SS + chunk * 32 + tid];
    if (tid == 0) s_scale = (cnt_ws[box] > 0) ? 1.0f : 0.0f;
    __syncthreads();
    const float scale = s_scale;

    const float4* F4 = (const float4*)(feats + (size_t)b * NN * CC);
    const float*  Pb = points + (size_t)b * NN * 3;

    #pragma unroll
    for (int s = 0; s < 4; ++s) {
        const int k   = hw + s * 8;       // sample within chunk, 0..31
        const int idx = s_idx[k];
        const float4 v = F4[idx * 32 + j];
        const int base = k * CH + 3 + 4 * j;
        s_buf[base + 0] = v.x * scale;
        s_buf[base + 1] = v.y * scale;
        s_buf[base + 2] = v.z * scale;
        s_buf[base + 3] = v.w * scale;
        if (j < 3) s_buf[k * CH + j] = Pb[idx * 3 + j] * scale;
    }
    __syncthreads();

    const vfloat4* src4 = (const vfloat4*)s_buf;
    vfloat4* dst4 = (vfloat4*)(out + (size_t)box * SS * CH + (size_t)chunk * 32 * CH);
    #pragma unroll
    for (int s = 0; s < 4; ++s)
        __builtin_nontemporal_store(src4[s * 256 + tid], &dst4[s * 256 + tid]);
    if (tid < 24)
        __builtin_nontemporal_store(src4[1024 + tid], &dst4[1024 + tid]);   // 1048 total
}

extern "C" void kernel_launch(void* const* d_in, const int* in_sizes, int n_in,
                              void* d_out, int out_size, void* d_ws, size_t ws_size,
                              hipStream_t stream) {
    const float* points = (const float*)d_in[0];
    const float* feats  = (const float*)d_in[1];
    const float* boxes  = (const float*)d_in[2];
    // d_in[3] = num_sampled_points, fixed at 512 by setup_inputs.

    int*  idx_ws = (int*)d_ws;                       // BM*SS ints = 1 MiB
    int*  cnt_ws = idx_ws + (size_t)BM * SS;         // BM ints
    float* out      = (float*)d_out;
    float* flag_out = out + (size_t)BM * SS * CH;    // empty_flag as float 0/1

    box_sample_kernel<<<BM, 512, 0, stream>>>(points, boxes, idx_ws, cnt_ws, flag_out);
    dim3 ggrid(BM, SS / 32);
    gather_kernel<<<ggrid, 256, 0, stream>>>(points, feats, idx_ws, cnt_ws, out);
}

// Round 7
// 198.000 us; speedup vs baseline: 1.0980x; 1.0341x over previous
//
#include <hip/hip_runtime.h>
#include <hip/hip_bf16.h>

// Problem constants (fixed by setup_inputs): B=4, N=16384, M=128, C=128, S=512.
// Output layout (float32): pooled (B*M*S*(C+3)) then empty_flag (B*M) as 0.0/1.0.
#define BB   4
#define NN   16384
#define MM   128
#define CC   128
#define SS   512
#define CH   (CC + 3)      // 131
#define BM   (BB * MM)     // 512
#define WAVES 8            // waves per box in kernel A
#define CHUNK (NN / WAVES) // 2048 points per wave

// ---------------------------------------------------------------------------
// Kernel A: one block (8 waves, 512 thr) per box.
// Each lane owns 4 consecutive points (48 B = 3 aligned float4 loads) ->
// 24 vector loads/thread instead of 96 scalar loads (A was VMEM-issue-bound).
// Stable compaction: group point order is (lane t major, u minor) = 4t+u, so
// pos = cnt + sum_u' popcll(M[u'] & lower(t)) + popc(m_t & ((1<<u)-1)).
// Waves merge by prefix offsets (stable), wrap-fill idx[k]=idx[k%cnt].
// Rotation test in double (true value >> fp32 ref roundoff); z-test fp32
// bit-identical to numpy.
// NOTE R5 lesson: do NOT fuse A+B (fused phase-B loses 8x gather TLP, +20us).
// NOTE R6 lesson: nontemporal stores on the output REGRESSED (+7us) — plain
// float4 stores are better here.
// ---------------------------------------------------------------------------
__global__ __launch_bounds__(512)
void box_sample_kernel(const float* __restrict__ points,  // (B,N,3)
                       const float* __restrict__ boxes,   // (B,M,7)
                       int*  __restrict__ idx_ws,         // (BM,SS)
                       int*  __restrict__ cnt_ws,         // (BM)
                       float* __restrict__ flag_out)      // (BM)
{
    const int box  = blockIdx.x;          // b*MM + m
    const int b    = box >> 7;            // MM = 128
    const int lane = threadIdx.x & 63;
    const int w    = threadIdx.x >> 6;    // wave 0..7

    const float4* P4 = (const float4*)(points + (size_t)b * NN * 3);  // 12288 f4/batch
    const float*  bx = boxes + (size_t)box * 7;

    const float cx = bx[0], cy = bx[1], cz = bx[2];
    const float dx = bx[3], dy = bx[4], dz = bx[5], rz = bx[6];

    const float  czc = cz + dz * 0.5f;     // exact
    const float  hz  = dz * 0.5f;          // exact
    const double ca  = cos(-(double)rz);
    const double sa  = sin(-(double)rz);
    const double hx  = (double)dx * 0.5;
    const double hy  = (double)dy * 0.5;

    __shared__ int s_part[WAVES][SS];     // 16 KB
    __shared__ int s_cnt[WAVES];
    __shared__ int s_idx[SS];

    int cnt = 0;
    const int pbase = w * CHUNK;
    for (int i0 = 0; i0 < CHUNK; i0 += 256) {     // 8 outer iterations
        const int pt0 = pbase + i0 + 4 * lane;    // first of this lane's 4 points
        const int f4b = (pt0 * 3) >> 2;           // pt0 % 4 == 0 -> exact
        const float4 q0 = P4[f4b + 0];   // p0.x p0.y p0.z p1.x
        const float4 q1 = P4[f4b + 1];   // p1.y p1.z p2.x p2.y
        const float4 q2 = P4[f4b + 2];   // p2.z p3.x p3.y p3.z
        const float px[4] = {q0.x, q0.w, q1.z, q2.y};
        const float py[4] = {q0.y, q1.x, q1.w, q2.z};
        const float pz[4] = {q0.z, q1.y, q2.x, q2.w};

        unsigned m = 0;
        #pragma unroll
        for (int u = 0; u < 4; ++u) {
            const double sx = (double)px[u] - (double)cx;
            const double sy = (double)py[u] - (double)cy;
            const float  szf = pz[u] - czc;
            const double lx = sx * ca - sy * sa;
            const double ly = sx * sa + sy * ca;
            const bool inside = (fabs(lx) < hx) && (fabs(ly) < hy) && (fabsf(szf) <= hz);
            m |= (unsigned)inside << u;
        }

        unsigned long long M[4];
        #pragma unroll
        for (int u = 0; u < 4; ++u) M[u] = __ballot((m >> u) & 1u);

        const unsigned long long lower = (1ull << lane) - 1ull;
        int lanebase = cnt;
        #pragma unroll
        for (int u = 0; u < 4; ++u) lanebase += __popcll(M[u] & lower);

        #pragma unroll
        for (int u = 0; u < 4; ++u) {
            if ((m >> u) & 1u) {
                const int pos = lanebase + __builtin_popcount(m & ((1u << u) - 1u));
                if (pos < SS) s_part[w][pos] = pt0 + u;
            }
        }
        #pragma unroll
        for (int u = 0; u < 4; ++u) cnt += __popcll(M[u]);
    }
    if (lane == 0) s_cnt[w] = cnt;
    __syncthreads();

    int c[WAVES], off[WAVES];
    int total = 0;
    #pragma unroll
    for (int q = 0; q < WAVES; ++q) { c[q] = s_cnt[q]; off[q] = total; total += c[q]; }

    // merge segments into first min(total,SS) slots, stable order
    for (int k = threadIdx.x; k < SS; k += 512) {
        int v = 0;
        #pragma unroll
        for (int q = 0; q < WAVES; ++q) {
            const int r = k - off[q];
            if (r >= 0 && r < c[q]) v = s_part[q][r];
        }
        s_idx[k] = v;
    }
    __syncthreads();

    if (total > 0 && total < SS) {
        for (int k = total + threadIdx.x; k < SS; k += 512)
            s_idx[k] = s_idx[k % total];
        __syncthreads();
    }

    int* dst = idx_ws + (size_t)box * SS;
    for (int k = threadIdx.x; k < SS; k += 512) dst[k] = s_idx[k];
    if (threadIdx.x == 0) {
        cnt_ws[box]   = total;
        flag_out[box] = (total == 0) ? 1.0f : 0.0f;
    }
}

// ---------------------------------------------------------------------------
// Kernel B (R3 form — best measured): grid (512 boxes, 16 chunks of 32
// samples); 256 threads. Phase 1: float4 gathers from feats staged into an
// LDS image of the chunk's 4192-float output span. Phase 2: perfectly
// coalesced plain float4 stores (NT stores regressed — R6).
// ---------------------------------------------------------------------------
__global__ __launch_bounds__(256)
void gather_kernel(const float* __restrict__ points,   // (B,N,3)
                   const float* __restrict__ feats,    // (B,N,C)
                   const int*   __restrict__ idx_ws,   // (BM,SS)
                   const int*   __restrict__ cnt_ws,   // (BM)
                   float* __restrict__ out)            // (BM,SS,CH)
{
    const int box   = blockIdx.x;         // 0..511
    const int chunk = blockIdx.y;         // 0..15
    const int b     = box >> 7;
    const int tid   = threadIdx.x;
    const int hw    = tid >> 5;           // half-wave 0..7
    const int j     = tid & 31;           // lane in half-wave

    __shared__ int   s_idx[32];
    __shared__ float s_scale;
    __shared__ __align__(16) float s_buf[32 * CH];   // 4192 floats = 16768 B

    if (tid < 32) s_idx[tid] = idx_ws[(size_t)box * SS + chunk * 32 + tid];
    if (tid == 0) s_scale = (cnt_ws[box] > 0) ? 1.0f : 0.0f;
    __syncthreads();
    const float scale = s_scale;

    const float4* F4 = (const float4*)(feats + (size_t)b * NN * CC);
    const float*  Pb = points + (size_t)b * NN * 3;

    #pragma unroll
    for (int s = 0; s < 4; ++s) {
        const int k   = hw + s * 8;       // sample within chunk, 0..31
        const int idx = s_idx[k];
        const float4 v = F4[idx * 32 + j];
        const int base = k * CH + 3 + 4 * j;
        s_buf[base + 0] = v.x * scale;
        s_buf[base + 1] = v.y * scale;
        s_buf[base + 2] = v.z * scale;
        s_buf[base + 3] = v.w * scale;
        if (j < 3) s_buf[k * CH + j] = Pb[idx * 3 + j] * scale;
    }
    __syncthreads();

    const float4* src4 = (const float4*)s_buf;
    float4* dst4 = (float4*)(out + (size_t)box * SS * CH + (size_t)chunk * 32 * CH);
    #pragma unroll
    for (int s = 0; s < 4; ++s) dst4[s * 256 + tid] = src4[s * 256 + tid];
    if (tid < 24) dst4[1024 + tid] = src4[1024 + tid];   // 1048 total
}

extern "C" void kernel_launch(void* const* d_in, const int* in_sizes, int n_in,
                              void* d_out, int out_size, void* d_ws, size_t ws_size,
                              hipStream_t stream) {
    const float* points = (const float*)d_in[0];
    const float* feats  = (const float*)d_in[1];
    const float* boxes  = (const float*)d_in[2];
    // d_in[3] = num_sampled_points, fixed at 512 by setup_inputs.

    int*  idx_ws = (int*)d_ws;                       // BM*SS ints = 1 MiB
    int*  cnt_ws = idx_ws + (size_t)BM * SS;         // BM ints
    float* out      = (float*)d_out;
    float* flag_out = out + (size_t)BM * SS * CH;    // empty_flag as float 0/1

    box_sample_kernel<<<BM, 512, 0, stream>>>(points, boxes, idx_ws, cnt_ws, flag_out);
    dim3 ggrid(BM, SS / 32);
    gather_kernel<<<ggrid, 256, 0, stream>>>(points, feats, idx_ws, cnt_ws, out);
}

// Round 8
// 195.381 us; speedup vs baseline: 1.1127x; 1.0134x over previous
//
#include <hip/hip_runtime.h>
#include <hip/hip_bf16.h>

// Problem constants (fixed by setup_inputs): B=4, N=16384, M=128, C=128, S=512.
// Output layout (float32): pooled (B*M*S*(C+3)) then empty_flag (B*M) as 0.0/1.0.
#define BB   4
#define NN   16384
#define MM   128
#define CC   128
#define SS   512
#define CH   (CC + 3)      // 131
#define BM   (BB * MM)     // 512
#define WAVES 8            // waves per box in kernel A
#define CHUNK (NN / WAVES) // 2048 points per wave

// Session lessons (keep):
//  R5: fusing A+B into one kernel loses 8x gather TLP -> +20us. Don't.
//  R6: nontemporal output stores -> +7us. Don't.
//  R7: vectorizing A's point loads was neutral -> A is not VMEM-issue-bound.
//  R8 theory: B's LDS staging had 4-way bank conflicts on 64 ds_write_b32
//      per wave (~685 DS cyc/wave, ~36us/CU at 128 waves/CU) -> drop LDS.

// ---------------------------------------------------------------------------
// Kernel A: one block (8 waves, 512 thr) per box.
// Each lane owns 4 consecutive points (48 B = 3 aligned float4 loads).
// Stable compaction: group point order is (lane t major, u minor) = 4t+u, so
// pos = cnt + sum_u' popcll(M[u'] & lower(t)) + popc(m & ((1<<u)-1)).
// Waves merge by prefix offsets (stable), wrap-fill idx[k]=idx[k%cnt].
// Rotation test in double (true value >> fp32 ref roundoff); z-test fp32
// bit-identical to numpy.
// ---------------------------------------------------------------------------
__global__ __launch_bounds__(512)
void box_sample_kernel(const float* __restrict__ points,  // (B,N,3)
                       const float* __restrict__ boxes,   // (B,M,7)
                       int*  __restrict__ idx_ws,         // (BM,SS)
                       int*  __restrict__ cnt_ws,         // (BM)
                       float* __restrict__ flag_out)      // (BM)
{
    const int box  = blockIdx.x;          // b*MM + m
    const int b    = box >> 7;            // MM = 128
    const int lane = threadIdx.x & 63;
    const int w    = threadIdx.x >> 6;    // wave 0..7

    const float4* P4 = (const float4*)(points + (size_t)b * NN * 3);
    const float*  bx = boxes + (size_t)box * 7;

    const float cx = bx[0], cy = bx[1], cz = bx[2];
    const float dx = bx[3], dy = bx[4], dz = bx[5], rz = bx[6];

    const float  czc = cz + dz * 0.5f;     // exact
    const float  hz  = dz * 0.5f;          // exact
    const double ca  = cos(-(double)rz);
    const double sa  = sin(-(double)rz);
    const double hx  = (double)dx * 0.5;
    const double hy  = (double)dy * 0.5;

    __shared__ int s_part[WAVES][SS];     // 16 KB
    __shared__ int s_cnt[WAVES];
    __shared__ int s_idx[SS];

    int cnt = 0;
    const int pbase = w * CHUNK;
    for (int i0 = 0; i0 < CHUNK; i0 += 256) {     // 8 outer iterations
        const int pt0 = pbase + i0 + 4 * lane;    // first of this lane's 4 points
        const int f4b = (pt0 * 3) >> 2;           // pt0 % 4 == 0 -> exact
        const float4 q0 = P4[f4b + 0];   // p0.x p0.y p0.z p1.x
        const float4 q1 = P4[f4b + 1];   // p1.y p1.z p2.x p2.y
        const float4 q2 = P4[f4b + 2];   // p2.z p3.x p3.y p3.z
        const float px[4] = {q0.x, q0.w, q1.z, q2.y};
        const float py[4] = {q0.y, q1.x, q1.w, q2.z};
        const float pz[4] = {q0.z, q1.y, q2.x, q2.w};

        unsigned m = 0;
        #pragma unroll
        for (int u = 0; u < 4; ++u) {
            const double sx = (double)px[u] - (double)cx;
            const double sy = (double)py[u] - (double)cy;
            const float  szf = pz[u] - czc;
            const double lx = sx * ca - sy * sa;
            const double ly = sx * sa + sy * ca;
            const bool inside = (fabs(lx) < hx) && (fabs(ly) < hy) && (fabsf(szf) <= hz);
            m |= (unsigned)inside << u;
        }

        unsigned long long M[4];
        #pragma unroll
        for (int u = 0; u < 4; ++u) M[u] = __ballot((m >> u) & 1u);

        const unsigned long long lower = (1ull << lane) - 1ull;
        int lanebase = cnt;
        #pragma unroll
        for (int u = 0; u < 4; ++u) lanebase += __popcll(M[u] & lower);

        #pragma unroll
        for (int u = 0; u < 4; ++u) {
            if ((m >> u) & 1u) {
                const int pos = lanebase + __builtin_popcount(m & ((1u << u) - 1u));
                if (pos < SS) s_part[w][pos] = pt0 + u;
            }
        }
        #pragma unroll
        for (int u = 0; u < 4; ++u) cnt += __popcll(M[u]);
    }
    if (lane == 0) s_cnt[w] = cnt;
    __syncthreads();

    int c[WAVES], off[WAVES];
    int total = 0;
    #pragma unroll
    for (int q = 0; q < WAVES; ++q) { c[q] = s_cnt[q]; off[q] = total; total += c[q]; }

    // merge segments into first min(total,SS) slots, stable order
    for (int k = threadIdx.x; k < SS; k += 512) {
        int v = 0;
        #pragma unroll
        for (int q = 0; q < WAVES; ++q) {
            const int r = k - off[q];
            if (r >= 0 && r < c[q]) v = s_part[q][r];
        }
        s_idx[k] = v;
    }
    __syncthreads();

    if (total > 0 && total < SS) {
        for (int k = total + threadIdx.x; k < SS; k += 512)
            s_idx[k] = s_idx[k % total];
        __syncthreads();
    }

    int* dst = idx_ws + (size_t)box * SS;
    for (int k = threadIdx.x; k < SS; k += 512) dst[k] = s_idx[k];
    if (threadIdx.x == 0) {
        cnt_ws[box]   = total;
        flag_out[box] = (total == 0) ? 1.0f : 0.0f;
    }
}

// ---------------------------------------------------------------------------
// Kernel B: direct-store gather — NO LDS, NO barriers. Grid (512 boxes,
// 16 chunks of 32 samples); 256 threads = 8 half-waves. Each half-wave owns
// 4 samples: 4 independent float4 gathers issued back-to-back (max MLP),
// then 16 stride-16B dword stores per thread; the 4 consecutive store
// instructions densely cover each sample's 512 B span (L2 write-combines).
// Avoids the 4-way LDS bank conflicts of the staged version.
// ---------------------------------------------------------------------------
__global__ __launch_bounds__(256)
void gather_kernel(const float* __restrict__ points,   // (B,N,3)
                   const float* __restrict__ feats,    // (B,N,C)
                   const int*   __restrict__ idx_ws,   // (BM,SS)
                   const int*   __restrict__ cnt_ws,   // (BM)
                   float* __restrict__ out)            // (BM,SS,CH)
{
    const int box   = blockIdx.x;         // 0..511
    const int chunk = blockIdx.y;         // 0..15
    const int b     = box >> 7;
    const int tid   = threadIdx.x;
    const int hw    = tid >> 5;           // half-wave 0..7
    const int j     = tid & 31;           // lane in half-wave

    const float scale = (cnt_ws[box] > 0) ? 1.0f : 0.0f;
    const int* idxp = idx_ws + (size_t)box * SS + chunk * 32;

    int k[4], idx[4];
    #pragma unroll
    for (int s = 0; s < 4; ++s) { k[s] = hw + s * 8; idx[s] = idxp[k[s]]; }

    const float4* F4 = (const float4*)(feats + (size_t)b * NN * CC);
    const float*  Pb = points + (size_t)b * NN * 3;

    float4 v[4];
    #pragma unroll
    for (int s = 0; s < 4; ++s) v[s] = F4[idx[s] * 32 + j];

    float p[4];
    #pragma unroll
    for (int s = 0; s < 4; ++s) p[s] = (j < 3) ? Pb[idx[s] * 3 + j] : 0.0f;

    float* dstbox = out + (size_t)box * SS * CH + (size_t)chunk * 32 * CH;
    #pragma unroll
    for (int s = 0; s < 4; ++s) {
        float* d = dstbox + k[s] * CH;
        d[3 + 4 * j + 0] = v[s].x * scale;
        d[3 + 4 * j + 1] = v[s].y * scale;
        d[3 + 4 * j + 2] = v[s].z * scale;
        d[3 + 4 * j + 3] = v[s].w * scale;
        if (j < 3) d[j] = p[s] * scale;
    }
}

extern "C" void kernel_launch(void* const* d_in, const int* in_sizes, int n_in,
                              void* d_out, int out_size, void* d_ws, size_t ws_size,
                              hipStream_t stream) {
    const float* points = (const float*)d_in[0];
    const float* feats  = (const float*)d_in[1];
    const float* boxes  = (const float*)d_in[2];
    // d_in[3] = num_sampled_points, fixed at 512 by setup_inputs.

    int*  idx_ws = (int*)d_ws;                       // BM*SS ints = 1 MiB
    int*  cnt_ws = idx_ws + (size_t)BM * SS;         // BM ints
    float* out      = (float*)d_out;
    float* flag_out = out + (size_t)BM * SS * CH;    // empty_flag as float 0/1

    box_sample_kernel<<<BM, 512, 0, stream>>>(points, boxes, idx_ws, cnt_ws, flag_out);
    dim3 ggrid(BM, SS / 32);
    gather_kernel<<<ggrid, 256, 0, stream>>>(points, feats, idx_ws, cnt_ws, out);
}